// Round 10
// baseline (148.385 us; speedup 1.0000x reference)
//
#include <hip/hip_runtime.h>
#include <hip/hip_bf16.h>

using f32x4 = __attribute__((ext_vector_type(4))) float;
using s16x8 = __attribute__((ext_vector_type(8))) short;

#define MFMA16x16x32(a, b, c) __builtin_amdgcn_mfma_f32_16x16x32_bf16((a), (b), (c), 0, 0, 0)

#define AS_G(p) ((const __attribute__((address_space(1))) void*)(p))
#define AS_L(p) ((__attribute__((address_space(3))) void*)(p))

// barrier with LDS-visibility only: does NOT drain vmcnt
#define BARRIER_LGKM() do { \
    asm volatile("s_waitcnt lgkmcnt(0)" ::: "memory"); \
    __builtin_amdgcn_s_barrier(); \
} while (0)

static __device__ __forceinline__ unsigned short f2bf(float f) {
    unsigned int u = __float_as_uint(f);
    u = (u + 0x7fffu + ((u >> 16) & 1u)) >> 16;
    return (unsigned short)u;
}
static __device__ __forceinline__ unsigned int cvt_pk_bf2(float lo, float hi) {
    unsigned int r;
    asm("v_cvt_pk_bf16_f32 %0, %1, %2" : "=v"(r) : "v"(lo), "v"(hi));
    return r;
}
// swizzled byte offset — used IDENTICALLY on write and read sides
static __device__ __forceinline__ int swz128(int r, int c) { return (r * 128 + c) ^ ((r & 7) << 4); }

// ---- convert fp32 -> bf16 (vectorized) ----
__global__ void cvt_f32_bf16(const float* __restrict__ in, unsigned short* __restrict__ out, int n) {
    int i = (blockIdx.x * blockDim.x + threadIdx.x) * 4;
    int stride = gridDim.x * blockDim.x * 4;
    for (; i < n; i += stride) {
        float4 v = *(const float4*)(in + i);
        ushort4 o;
        o.x = f2bf(v.x); o.y = f2bf(v.y); o.z = f2bf(v.z); o.w = f2bf(v.w);
        *(ushort4*)(out + i) = o;
    }
}

// ---- LDS-tiled transpose+convert: wt[n][k] = bf16(w[k][n]) ----
__global__ __launch_bounds__(256)
void transpose_cvt_tiled(const float* __restrict__ w, unsigned short* __restrict__ wt,
                         int K, int N) {
    __shared__ float tile[32][33];
    const int tid = threadIdx.x;
    const int tx = tid & 31, ty = tid >> 5;
    const int n0 = blockIdx.x * 32, k0 = blockIdx.y * 32;
#pragma unroll
    for (int r = 0; r < 4; r++)
        tile[ty * 4 + r][tx] = w[(size_t)(k0 + ty * 4 + r) * N + n0 + tx];
    __syncthreads();
#pragma unroll
    for (int r = 0; r < 4; r++)
        wt[(size_t)(n0 + ty * 4 + r) * K + k0 + tx] = f2bf(tile[tx][ty * 4 + r]);
}

// ---- GEMM: C[M,N] = A[M,K] * Bt[N,K]^T + bias ----
// 128x128 tile, BK=64, 2-phase dbuf gload_lds staging with COUNTED vmcnt:
// STAGE(t+1); vmcnt(8) (t's loads landed, t+1's stay in flight); barrier;
// compute(t); barrier. Drain to 0 only on the last iteration.
template <bool OUT_BF16>
__global__ __launch_bounds__(256, 2)
void gemm_bt(const unsigned short* __restrict__ A, const unsigned short* __restrict__ Bt,
             const float* __restrict__ bias, void* __restrict__ Cout,
             unsigned short* __restrict__ Vt,
             int M, int N, int K, int ldc, int qcols, float qscale) {
    __shared__ char smem[65536];
    const int tid = threadIdx.x, wid = tid >> 6, lane = tid & 63;
    const int g = lane >> 4, lr = lane & 15;
    const int m0 = blockIdx.y * 128, n0 = blockIdx.x * 128;
    const int wm = wid >> 1, wn = wid & 1;

    f32x4 acc[4][4];
#pragma unroll
    for (int i = 0; i < 4; i++)
#pragma unroll
        for (int j = 0; j < 4; j++) acc[i][j] = f32x4{0.f, 0.f, 0.f, 0.f};

    const int rbase = lane >> 3;
    const int cSw = ((lane & 7) << 4) ^ (rbase << 4);

    auto STAGE = [&](int buf, int kt) {
        char* base = smem + buf * 32768;
#pragma unroll
        for (int ww = 0; ww < 4; ww++) {
            int w = wid * 4 + ww;
            int r = w * 8 + rbase;
            const unsigned short* srcA = A + (size_t)(m0 + r) * K + kt + (cSw >> 1);
            __builtin_amdgcn_global_load_lds(AS_G(srcA), AS_L(base + w * 1024), 16, 0, 0);
            const unsigned short* srcB = Bt + (size_t)(n0 + r) * K + kt + (cSw >> 1);
            __builtin_amdgcn_global_load_lds(AS_G(srcB), AS_L(base + 16384 + w * 1024), 16, 0, 0);
        }
    };

    const int nk = K >> 6;
    STAGE(0, 0);

    for (int t = 0; t < nk; t++) {
        if (t + 1 < nk) {
            STAGE((t + 1) & 1, (t + 1) << 6);
            asm volatile("s_waitcnt vmcnt(8)" ::: "memory");   // t's 8 loads done
        } else {
            asm volatile("s_waitcnt vmcnt(0)" ::: "memory");
        }
        __builtin_amdgcn_s_barrier();
        char* cbase = smem + (t & 1) * 32768;
#pragma unroll
        for (int ks = 0; ks < 2; ks++) {
            s16x8 af[4], bfr[4];
#pragma unroll
            for (int i = 0; i < 4; i++)
                af[i] = *(const s16x8*)(cbase + swz128(wm * 64 + i * 16 + lr, ks * 64 + g * 16));
#pragma unroll
            for (int j = 0; j < 4; j++)
                bfr[j] = *(const s16x8*)(cbase + 16384 + swz128(wn * 64 + j * 16 + lr, ks * 64 + g * 16));
#pragma unroll
            for (int i = 0; i < 4; i++)
#pragma unroll
                for (int j = 0; j < 4; j++)
                    acc[i][j] = MFMA16x16x32(af[i], bfr[j], acc[i][j]);
        }
        BARRIER_LGKM();   // all waves done reading buf[t&1] before t+2 lands there
    }

#pragma unroll
    for (int j = 0; j < 4; j++) {
        int c = n0 + wn * 64 + j * 16 + lr;
        float bv = bias[c];
        float cscale = (c < qcols) ? qscale : 1.0f;
        if (Vt != nullptr && c >= 1536) {
            int h = (c - 1536) >> 6, d = (c - 1536) & 63;
#pragma unroll
            for (int i = 0; i < 4; i++) {
                int r0 = m0 + wm * 64 + i * 16 + g * 4;
                int bb = r0 >> 11, t0 = r0 & 2047;
                ushort4 o4;
                o4.x = f2bf(acc[i][j][0] + bv);
                o4.y = f2bf(acc[i][j][1] + bv);
                o4.z = f2bf(acc[i][j][2] + bv);
                o4.w = f2bf(acc[i][j][3] + bv);
                *(ushort4*)(Vt + ((((size_t)bb * 12 + h) * 64 + d) << 11) + t0) = o4;
            }
        } else {
#pragma unroll
            for (int i = 0; i < 4; i++) {
#pragma unroll
                for (int rg = 0; rg < 4; rg++) {
                    int r = m0 + wm * 64 + i * 16 + g * 4 + rg;
                    float val = (acc[i][j][rg] + bv) * cscale;
                    if constexpr (OUT_BF16)
                        ((unsigned short*)Cout)[(size_t)r * ldc + c] = f2bf(val);
                    else
                        ((float*)Cout)[(size_t)r * ldc + c] = val;
                }
            }
        }
    }
}

// ---- causal flash attention, swapped QK^T + async K/V + XCD clustering ----
// Grid 1536 1-D, 1 q-tile/block: s -> xcd=s&7, i=s>>3, grp=xcd*6+(i>>5)
// (all 32 q-tiles of one (b,h) on ONE XCD -> K/V stay L2-resident).
// qt scramble r=(i+5*(i>>5))&31, qt = r&1 ? r>>1 : 31-(r>>1): alternates
// heavy/light so each CU's 6 co-resident blocks have ~equal total work.
// Q pre-scaled by 0.125*log2e in the GEMM epilogue -> P = exp2(S') directly.
__global__ __launch_bounds__(256, 2)
void attn_kernel(const unsigned short* __restrict__ qk, const unsigned short* __restrict__ Vt,
                 unsigned short* __restrict__ y) {
    __shared__ char smem[24576]; // K:[0,8K) Vtile:[8K,16K) P^T: 16K + wid*2K
    const int tid = threadIdx.x, wid = tid >> 6, lane = tid & 63;
    const int g = lane >> 4, lr = lane & 15;
    const int T = 2048;

    const int s = blockIdx.x;
    const int xcd = s & 7, i = s >> 3;
    const int grp = xcd * 6 + (i >> 5);
    const int r0_ = (i + 5 * (i >> 5)) & 31;
    const int qt = (r0_ & 1) ? (r0_ >> 1) : (31 - (r0_ >> 1));
    const int h = grp % 12, b = grp / 12;
    const int q0 = qt * 64;

    const int krow = tid >> 2;
    const int kcol = (tid & 3) * 32;

    const unsigned short* qrow = qk + (size_t)(b * T + q0 + wid * 16 + lr) * 1536 + h * 64;
    s16x8 aq[2];
    aq[0] = *(const s16x8*)(qrow + g * 8);
    aq[1] = *(const s16x8*)(qrow + 32 + g * 8);

    float l_acc = 0.f;
    f32x4 o[4];
#pragma unroll
    for (int r = 0; r < 4; r++) o[r] = f32x4{0.f, 0.f, 0.f, 0.f};

    const unsigned short* pkBase = qk + (size_t)(b * T + krow) * 1536 + 768 + h * 64 + (kcol >> 1);
    const unsigned short* pvBase = Vt + ((((size_t)b * 12 + h) * 64 + krow) << 11) + (kcol >> 1);

    s16x8 k0 = *(const s16x8*)(pkBase);
    s16x8 k1 = *(const s16x8*)(pkBase + 8);
    s16x8 v0 = *(const s16x8*)(pvBase);
    s16x8 v1 = *(const s16x8*)(pvBase + 8);

    const int nt = qt + 1;
    for (int t = 0; t < nt; t++) {
        const int j0 = t * 64;
        BARRIER_LGKM();              // prior tile's LDS reads done
        *(s16x8*)(smem + swz128(krow, kcol)) = k0;
        *(s16x8*)(smem + swz128(krow, kcol + 16)) = k1;
        *(s16x8*)(smem + 8192 + swz128(krow, kcol)) = v0;
        *(s16x8*)(smem + 8192 + swz128(krow, kcol + 16)) = v1;
        if (t + 1 < nt) {
            const unsigned short* pk = pkBase + (size_t)(j0 + 64) * 1536;
            k0 = *(const s16x8*)(pk);
            k1 = *(const s16x8*)(pk + 8);
            const unsigned short* pv = pvBase + (j0 + 64);
            v0 = *(const s16x8*)(pv);
            v1 = *(const s16x8*)(pv + 8);
        }
        BARRIER_LGKM();              // staged tile visible; vmcnt NOT drained

        // S'^T = K Q^T (Q pre-scaled by 0.125*log2e)
        f32x4 st[4];
        __builtin_amdgcn_s_setprio(1);
#pragma unroll
        for (int nf = 0; nf < 4; nf++) {
            f32x4 sf = f32x4{0.f, 0.f, 0.f, 0.f};
#pragma unroll
            for (int ks = 0; ks < 2; ks++) {
                int jj = nf * 16 + lr;
                s16x8 ak = *(const s16x8*)(smem + swz128(jj, (ks * 32 + g * 8) * 2));
                sf = MFMA16x16x32(ak, aq[ks], sf);
            }
            st[nf] = sf;
        }
        __builtin_amdgcn_s_setprio(0);

        // P = exp2(S'), causal mask on diagonal tile
        const bool diag = (j0 == q0);
        const int q_rel = wid * 16 + lr;
#pragma unroll
        for (int nf = 0; nf < 4; nf++) {
#pragma unroll
            for (int rg = 0; rg < 4; rg++) {
                float p = exp2f(st[nf][rg]);
                if (diag && (nf * 16 + g * 4 + rg > q_rel)) p = 0.f;
                st[nf][rg] = p;
                l_acc += p;
            }
        }

        // P^T -> bf16 via v_cvt_pk -> wave-private LDS
        char* pbase = smem + 16384 + wid * 2048;
#pragma unroll
        for (int nf = 0; nf < 4; nf++) {
            uint2 dw;
            dw.x = cvt_pk_bf2(st[nf][0], st[nf][1]);
            dw.y = cvt_pk_bf2(st[nf][2], st[nf][3]);
            *(uint2*)(pbase + swz128(lr, nf * 32 + g * 8)) = dw;
        }
        s16x8 pf[2];
#pragma unroll
        for (int ks = 0; ks < 2; ks++)
            pf[ks] = *(const s16x8*)(pbase + swz128(lr, ks * 64 + g * 16));

        // O += P * V
        __builtin_amdgcn_s_setprio(1);
#pragma unroll
        for (int nf = 0; nf < 4; nf++) {
#pragma unroll
            for (int ks = 0; ks < 2; ks++) {
                int d = nf * 16 + lr;
                s16x8 bv = *(const s16x8*)(smem + 8192 + swz128(d, ks * 64 + g * 16));
                o[nf] = MFMA16x16x32(pf[ks], bv, o[nf]);
            }
        }
        __builtin_amdgcn_s_setprio(0);
    }

    // epilogue: row-sum across g-groups; redistribute 1/l; store
    float l = l_acc;
    l += __shfl_xor(l, 16, 64);
    l += __shfl_xor(l, 32, 64);
    float linv = 1.0f / l;
    float linv_q[4];
#pragma unroll
    for (int rg = 0; rg < 4; rg++)
        linv_q[rg] = __shfl(linv, (lane & 48) | (g * 4 + rg), 64);
#pragma unroll
    for (int nf = 0; nf < 4; nf++) {
#pragma unroll
        for (int rg = 0; rg < 4; rg++) {
            int row = b * T + q0 + wid * 16 + g * 4 + rg;
            int col = h * 64 + nf * 16 + lr;
            y[(size_t)row * 768 + col] = f2bf(o[nf][rg] * linv_q[rg]);
        }
    }
}

extern "C" void kernel_launch(void* const* d_in, const int* in_sizes, int n_in,
                              void* d_out, int out_size, void* d_ws, size_t ws_size,
                              hipStream_t stream) {
    const float* x      = (const float*)d_in[0];
    const float* w_attn = (const float*)d_in[1];
    const float* b_attn = (const float*)d_in[2];
    const float* w_proj = (const float*)d_in[3];
    const float* b_proj = (const float*)d_in[4];

    char* ws = (char*)d_ws;
    unsigned short* qk  = (unsigned short*)(ws);
    unsigned short* Vt  = (unsigned short*)(ws + 25165824);
    unsigned short* wTa = (unsigned short*)(ws + 37748736);
    unsigned short* wTp = (unsigned short*)(ws + 41287680);

    const bool big = ws_size >= (size_t)55050240;
    unsigned short* xb = (unsigned short*)d_out;
    unsigned short* yb = big ? (unsigned short*)(ws + 42467328)
                             : (unsigned short*)((char*)d_out + 12582912);
    float* projOut = big ? (float*)d_out : (float*)ws;

    cvt_f32_bf16<<<2048, 256, 0, stream>>>(x, xb, 8192 * 768);
    transpose_cvt_tiled<<<dim3(72, 24), 256, 0, stream>>>(w_attn, wTa, 768, 2304);
    transpose_cvt_tiled<<<dim3(24, 24), 256, 0, stream>>>(w_proj, wTp, 768, 768);

    // qscale = 0.125 * log2(e): softmax scale and exp->exp2 folded into Q
    gemm_bt<true><<<dim3(18, 64), 256, 0, stream>>>(xb, wTa, b_attn, (void*)qk, Vt,
                                                    8192, 2304, 768, 1536, 768, 0.1803368801111244f);
    attn_kernel<<<1536, 256, 0, stream>>>(qk, Vt, yb);
    gemm_bt<false><<<dim3(6, 64), 256, 0, stream>>>(yb, wTp, b_proj, (void*)projOut, nullptr,
                                                    8192, 768, 768, 768, 0, 1.0f);
    if (!big)
        hipMemcpyAsync(d_out, projOut, 25165824, hipMemcpyDeviceToDevice, stream);
}